// Round 1
// baseline (7138.852 us; speedup 1.0000x reference)
//
#include <hip/hip_runtime.h>
#include <stdint.h>

#define NN 8192
#define DD 64
#define KKDE 50
#define KRIPS 16
#define ROWS 8
#define CBUF 512

// ---------------- K1: squared norms (fmaf chain MUST match k_hist/k_cand dot) ----
__global__ __launch_bounds__(256) void k_sq(const float* __restrict__ x, float* __restrict__ sq){
  int i = blockIdx.x*256 + threadIdx.x;
  const float4* xr = (const float4*)(x + (size_t)i*DD);
  float acc = 0.f;
#pragma unroll
  for (int c=0;c<16;c++){
    float4 v = xr[c];
    acc = fmaf(v.x,v.x,acc); acc = fmaf(v.y,v.y,acc);
    acc = fmaf(v.z,v.z,acc); acc = fmaf(v.w,v.w,acc);
  }
  sq[i] = acc;
}

// ---------------- K2a: per-row histogram -> upper bound on 50th distance --------
__global__ __launch_bounds__(256) void k_hist(const float* __restrict__ x, const float* __restrict__ sq,
                                              float* __restrict__ Tub){
  __shared__ float xi[ROWS*DD];
  __shared__ float sqi[ROWS];
  __shared__ unsigned hist[ROWS*256];
  const int tid = threadIdx.x;
  const int i0 = blockIdx.x * ROWS;
  for (int t = tid; t < ROWS*DD; t += 256) xi[t] = x[(size_t)i0*DD + t];
  for (int t = tid; t < ROWS*256; t += 256) hist[t] = 0u;
  if (tid < ROWS) sqi[tid] = sq[i0 + tid];
  __syncthreads();
  for (int jo = 0; jo < NN; jo += 512){
    const int j = jo + tid*2;
    const float* xj = x + (size_t)j*DD;
    float acc0[ROWS], acc1[ROWS];
#pragma unroll
    for (int r=0;r<ROWS;r++){ acc0[r]=0.f; acc1[r]=0.f; }
#pragma unroll
    for (int c=0;c<16;c++){
      const float4 a = ((const float4*)xj)[c];
      const float4 b = ((const float4*)(xj+DD))[c];
#pragma unroll
      for (int r=0;r<ROWS;r++){
        const float4 wv = ((const float4*)(xi + r*DD))[c];
        acc0[r] = fmaf(a.x,wv.x,acc0[r]); acc0[r] = fmaf(a.y,wv.y,acc0[r]);
        acc0[r] = fmaf(a.z,wv.z,acc0[r]); acc0[r] = fmaf(a.w,wv.w,acc0[r]);
        acc1[r] = fmaf(b.x,wv.x,acc1[r]); acc1[r] = fmaf(b.y,wv.y,acc1[r]);
        acc1[r] = fmaf(b.z,wv.z,acc1[r]); acc1[r] = fmaf(b.w,wv.w,acc1[r]);
      }
    }
    const float sj0 = sq[j], sj1 = sq[j+1];
#pragma unroll
    for (int r=0;r<ROWS;r++){
      float d0 = (sqi[r] + sj0) - 2.f*acc0[r];
      float d1 = (sqi[r] + sj1) - 2.f*acc1[r];
      int b0 = min(255, max(0, (int)(d0*0.5f)));
      int b1 = min(255, max(0, (int)(d1*0.5f)));
      atomicAdd(&hist[r*256+b0], 1u);
      atomicAdd(&hist[r*256+b1], 1u);
    }
  }
  __syncthreads();
  if (tid < ROWS){
    unsigned cum = 0; int b = 255;
    for (int q = 0; q < 256; ++q){ cum += hist[tid*256+q]; if (cum >= KKDE){ b = q; break; } }
    Tub[i0+tid] = 2.f*(float)(b+1);
  }
}

// ---------------- K2b: collect candidates, exact top-50 via small bitonic -------
__global__ __launch_bounds__(256) void k_cand(const float* __restrict__ x, const float* __restrict__ sq,
                                              const float* __restrict__ Tub,
                                              float* __restrict__ res, unsigned short* __restrict__ nn16){
  __shared__ float xi[ROWS*DD];
  __shared__ float sqi[ROWS];
  __shared__ float tub[ROWS];
  __shared__ unsigned long long cand[ROWS*CBUF]; // 32KB
  __shared__ unsigned ccnt[ROWS];
  const int tid = threadIdx.x;
  const int i0 = blockIdx.x * ROWS;
  for (int t = tid; t < ROWS*DD; t += 256) xi[t] = x[(size_t)i0*DD + t];
  for (int t = tid; t < ROWS*CBUF; t += 256) cand[t] = ~0ULL;
  if (tid < ROWS){ sqi[tid] = sq[i0+tid]; tub[tid] = Tub[i0+tid]; ccnt[tid] = 0u; }
  __syncthreads();
  for (int jo = 0; jo < NN; jo += 512){
    const int j = jo + tid*2;
    const float* xj = x + (size_t)j*DD;
    float acc0[ROWS], acc1[ROWS];
#pragma unroll
    for (int r=0;r<ROWS;r++){ acc0[r]=0.f; acc1[r]=0.f; }
#pragma unroll
    for (int c=0;c<16;c++){
      const float4 a = ((const float4*)xj)[c];
      const float4 b = ((const float4*)(xj+DD))[c];
#pragma unroll
      for (int r=0;r<ROWS;r++){
        const float4 wv = ((const float4*)(xi + r*DD))[c];
        acc0[r] = fmaf(a.x,wv.x,acc0[r]); acc0[r] = fmaf(a.y,wv.y,acc0[r]);
        acc0[r] = fmaf(a.z,wv.z,acc0[r]); acc0[r] = fmaf(a.w,wv.w,acc0[r]);
        acc1[r] = fmaf(b.x,wv.x,acc1[r]); acc1[r] = fmaf(b.y,wv.y,acc1[r]);
        acc1[r] = fmaf(b.z,wv.z,acc1[r]); acc1[r] = fmaf(b.w,wv.w,acc1[r]);
      }
    }
    const float sj0 = sq[j], sj1 = sq[j+1];
#pragma unroll
    for (int r=0;r<ROWS;r++){
      float d0 = (sqi[r] + sj0) - 2.f*acc0[r];
      float d1 = (sqi[r] + sj1) - 2.f*acc1[r];
      if (d0 < tub[r]){
        unsigned pos = atomicAdd(&ccnt[r], 1u);
        if (pos < CBUF){
          unsigned u = __float_as_uint(d0);
          u = ((int)u < 0) ? ~u : (u | 0x80000000u);
          cand[r*CBUF+pos] = (((unsigned long long)u) << 13) | (unsigned)j;
        }
      }
      if (d1 < tub[r]){
        unsigned pos = atomicAdd(&ccnt[r], 1u);
        if (pos < CBUF){
          unsigned u = __float_as_uint(d1);
          u = ((int)u < 0) ? ~u : (u | 0x80000000u);
          cand[r*CBUF+pos] = (((unsigned long long)u) << 13) | (unsigned)(j+1);
        }
      }
    }
  }
  __syncthreads();
  // bitonic sort each row's 512 candidates ascending (key = d_bits<<13 | j)
  for (int k = 2; k <= CBUF; k <<= 1){
    for (int jj = k >> 1; jj > 0; jj >>= 1){
#pragma unroll
      for (int r = 0; r < ROWS; ++r){
        int m = tid;
        int i = ((m & ~(jj-1)) << 1) | (m & (jj-1));
        int p = i | jj;
        bool up = ((i & k) == 0);
        unsigned long long a = cand[r*CBUF+i], bb = cand[r*CBUF+p];
        if ((a > bb) == up){ cand[r*CBUF+i] = bb; cand[r*CBUF+p] = a; }
      }
      __syncthreads();
    }
  }
  // outputs: 4 waves, 2 rows each
  const int w = tid >> 6, lane = tid & 63;
  for (int rr = 0; rr < 2; ++rr){
    const int r = w*2 + rr;
    unsigned long long kk = cand[r*CBUF + lane];
    float e = 0.f;
    if (lane < KKDE){
      unsigned u = (unsigned)(kk >> 13);
      u = (u & 0x80000000u) ? (u & 0x7FFFFFFFu) : ~u;
      float d = __uint_as_float(u);
      e = expf(-d / 30.f);
    }
#pragma unroll
    for (int off = 32; off; off >>= 1) e += __shfl_down(e, off);
    if (lane == 0) res[i0+r] = e / 1500.f;
    if (lane < KRIPS) nn16[(size_t)(i0+r)*16 + lane] = (unsigned short)(kk & 8191ULL);
  }
}

// ---------------- K3: max of res ------------------------------------------------
__global__ __launch_bounds__(1024) void k_max(const float* __restrict__ res, float* __restrict__ maxr){
  __shared__ float s[1024];
  float m = 0.f;
  for (int t = threadIdx.x; t < NN; t += 1024) m = fmaxf(m, res[t]);
  s[threadIdx.x] = m; __syncthreads();
  for (int o = 512; o; o >>= 1){ if (threadIdx.x < o) s[threadIdx.x] = fmaxf(s[threadIdx.x], s[threadIdx.x+o]); __syncthreads(); }
  if (threadIdx.x == 0) maxr[0] = s[0];
}

// ---------------- K4: stable argsort of density via 64KB LDS bitonic ------------
__global__ __launch_bounds__(1024) void k_sort(const float* __restrict__ res, const float* __restrict__ maxr,
                                               unsigned* __restrict__ sidx, float* __restrict__ dens_s,
                                               unsigned short* __restrict__ rankv){
  __shared__ unsigned long long keys[NN]; // 64KB
  const float mr = maxr[0];
  for (int t = threadIdx.x; t < NN; t += 1024){
    float dnv = res[t] / mr; // positive -> bits monotonic
    keys[t] = (((unsigned long long)__float_as_uint(dnv)) << 13) | (unsigned)t;
  }
  __syncthreads();
  for (int k = 2; k <= NN; k <<= 1){
    for (int j = k >> 1; j > 0; j >>= 1){
      for (int m = threadIdx.x; m < NN/2; m += 1024){
        int i = ((m & ~(j-1)) << 1) | (m & (j-1));
        int p = i | j;
        bool up = ((i & k) == 0);
        unsigned long long a = keys[i], b = keys[p];
        if ((a > b) == up){ keys[i] = b; keys[p] = a; }
      }
      __syncthreads();
    }
  }
  for (int t = threadIdx.x; t < NN; t += 1024){
    unsigned long long kk = keys[t];
    unsigned idx = (unsigned)(kk & 8191ULL);
    sidx[t] = idx;
    dens_s[t] = __uint_as_float((unsigned)(kk >> 13));
    rankv[idx] = (unsigned short)t;
  }
}

// ---------------- K5: upward neighbor lists in sorted order ---------------------
__global__ __launch_bounds__(256) void k_ups(const unsigned* __restrict__ sidx, const unsigned short* __restrict__ rankv,
                                             const unsigned short* __restrict__ nn16, unsigned short* __restrict__ ups){
  int p = blockIdx.x*256 + threadIdx.x;
  unsigned orig = sidx[p];
  unsigned short out[16];
  int cnt = 0;
#pragma unroll
  for (int k = 0; k < 16; ++k){
    unsigned r = rankv[nn16[(size_t)orig*16 + k]];
    if ((int)r > p) out[cnt++] = (unsigned short)r;
  }
  for (int k = cnt; k < 16; ++k) out[k] = 0xFFFFu;
#pragma unroll
  for (int k = 0; k < 16; ++k) ups[(size_t)p*16 + k] = out[k];
}

// ---------------- K6: single-wave union-find sweep (LDS-resident) ---------------
__device__ __forceinline__ int uf_find(volatile unsigned short* par, int x){
  int r = par[x];
  if (r == x) return x;
  int g = par[r];
  while (g != r){ r = g; g = par[r]; }
  int c = x;
  while (c != r){ int nx = par[c]; par[c] = (unsigned short)r; c = nx; }
  return r;
}

__global__ __launch_bounds__(64) void k_uf(const unsigned short* __restrict__ ups, int* __restrict__ death_out){
  __shared__ __align__(16) unsigned short chunk[1024*16]; // 32KB
  __shared__ unsigned short parent[NN];                   // 16KB
  __shared__ unsigned short death[NN];                    // 16KB
  volatile unsigned short* par = parent;
  const int lane = threadIdx.x;
  for (int t = lane; t < NN; t += 64){ parent[t] = (unsigned short)t; death[t] = 0xFFFFu; }
  __syncthreads();
  for (int base = NN-1024; base >= 0; base -= 1024){
    // stage next 1024 iterations' upward lists into LDS
    const uint4* src = (const uint4*)(ups + (size_t)base*16);
    uint4* dst = (uint4*)chunk;
    for (int t = lane; t < 2048; t += 64) dst[t] = src[t];
    __syncthreads();
    // periodic full path compression keeps find chains ~1
    for (int t = lane; t < NN; t += 64){
      int r = t, pp = par[t];
      while (pp != r){ r = pp; pp = par[r]; }
      par[t] = (unsigned short)r;
    }
    __syncthreads();
    const int pend = (base + 1024 >= NN) ? (NN-2) : (base + 1023);
    for (int p = pend; p >= base; --p){
      unsigned u = (lane < 16) ? (unsigned)chunk[((p - base) << 4) + lane] : 0xFFFFu;
      const bool active = (u != 0xFFFFu);
      if (__ballot(active) == 0ULL) continue;      // no upward neighbours
      int root = 0;
      if (active) root = uf_find(par, (int)u);
      // max upward neighbour carries its root: key = u<<13 | root (u distinct)
      unsigned key = active ? ((u << 13) | (unsigned)root) : 0u;
#pragma unroll
      for (int off = 32; off; off >>= 1){
        unsigned o = (unsigned)__shfl_xor((int)key, off);
        key = key > o ? key : o;
      }
      const int r_up = (int)(key & 8191u);
      if (lane == 0) par[p] = (unsigned short)r_up;        // attach p
      if (active && root != r_up){
        // threshold=1.0 always merges; duplicate roots write identical values
        death[root] = (unsigned short)p;
        par[root] = (unsigned short)r_up;
      }
    }
    __syncthreads();
  }
  for (int t = lane; t < NN; t += 64){
    unsigned short d = death[t];
    death_out[t] = (d == 0xFFFFu) ? -1 : (int)d;
  }
}

// ---------------- K7: loss (sum + top-10 by (pers, entry) lexicographic) --------
__global__ __launch_bounds__(1024) void k_loss(const int* __restrict__ death, const float* __restrict__ dens_s,
                                               float* __restrict__ out){
  __shared__ float sred[1024];
  __shared__ unsigned long long kred[1024];
  __shared__ unsigned long long sel[10];
  const int tid = threadIdx.x;
  float s = 0.f;
  for (int e = tid; e < NN; e += 1024){
    int dr = death[e];
    if (dr >= 0) s += dens_s[e] - dens_s[dr];
  }
  sred[tid] = s; __syncthreads();
  for (int o = 512; o; o >>= 1){ if (tid < o) sred[tid] += sred[tid+o]; __syncthreads(); }
  const float S = sred[0];
  unsigned long long last = ~0ULL;
  for (int t = 0; t < 10; ++t){
    unsigned long long km = 0ULL;
    for (int e = tid; e < NN; e += 1024){
      int dr = death[e];
      if (dr >= 0){
        float pers = dens_s[e] - dens_s[dr]; // >= 0
        unsigned long long k = (((unsigned long long)__float_as_uint(pers)) << 13) | (unsigned)e;
        if (k < last && k > km) km = k;
      }
    }
    kred[tid] = km; __syncthreads();
    for (int o = 512; o; o >>= 1){ if (tid < o) kred[tid] = (kred[tid] > kred[tid+o]) ? kred[tid] : kred[tid+o]; __syncthreads(); }
    unsigned long long st = kred[0];
    if (tid == 0) sel[t] = st;
    last = st;
    __syncthreads();
  }
  if (tid == 0){
    float top = 0.f;
    for (int t = 0; t < 10; ++t){
      if (sel[t]) top += __uint_as_float((unsigned)(sel[t] >> 13));
    }
    float strong = 0.f, dest0 = 0.f, dest1 = 0.f;
    if (sel[0]){
      unsigned e0 = (unsigned)(sel[0] & 8191ULL);
      dest0 = dens_s[e0]; dest1 = dens_s[death[e0]];
    }
    for (int t = 1; t < 10; ++t){
      if (!sel[t]) continue;
      unsigned e = (unsigned)(sel[t] & 8191ULL);
      float a = dens_s[e] - dest0;
      float b = dens_s[death[e]] - dest1;
      strong += sqrtf(a*a + b*b);
    }
    float weak = (S - top) / 1.41421356237309515f;
    out[0] = weak + strong;
  }
}

// ---------------- launch --------------------------------------------------------
extern "C" void kernel_launch(void* const* d_in, const int* in_sizes, int n_in,
                              void* d_out, int out_size, void* d_ws, size_t ws_size,
                              hipStream_t stream){
  const float* x = (const float*)d_in[0];
  char* w = (char*)d_ws;
  // workspace layout (737,536 bytes total)
  float*          sq     = (float*)(w + 0);
  float*          res    = (float*)(w + 32768);
  float*          maxr   = (float*)(w + 65536);
  float*          Tub    = (float*)(w + 65792);
  unsigned*       sidx   = (unsigned*)(w + 98560);
  float*          dens_s = (float*)(w + 131328);
  unsigned short* rankv  = (unsigned short*)(w + 164096);
  unsigned short* nn16   = (unsigned short*)(w + 180480);
  unsigned short* ups    = (unsigned short*)(w + 442624);
  int*            death  = (int*)(w + 704768);

  k_sq  <<<NN/256, 256, 0, stream>>>(x, sq);
  k_hist<<<NN/ROWS, 256, 0, stream>>>(x, sq, Tub);
  k_cand<<<NN/ROWS, 256, 0, stream>>>(x, sq, Tub, res, nn16);
  k_max <<<1, 1024, 0, stream>>>(res, maxr);
  k_sort<<<1, 1024, 0, stream>>>(res, maxr, sidx, dens_s, rankv);
  k_ups <<<NN/256, 256, 0, stream>>>(sidx, rankv, nn16, ups);
  k_uf  <<<1, 64, 0, stream>>>(ups, death);
  k_loss<<<1, 1024, 0, stream>>>(death, dens_s, (float*)d_out);
}

// Round 2
// 2219.419 us; speedup vs baseline: 3.2165x; 3.2165x over previous
//
#include <hip/hip_runtime.h>
#include <stdint.h>

#define NN 8192
#define DD 64
#define KKDE 50
#define KRIPS 16
#define ROWS 8
#define ROWS_C 4
#define CBUF 1024
#define SBUF 1024

// ---------------- K1: squared norms (fmaf chain MUST match k_cand dot) ----------
__global__ __launch_bounds__(256) void k_sq(const float* __restrict__ x, float* __restrict__ sq){
  int i = blockIdx.x*256 + threadIdx.x;
  const float4* xr = (const float4*)(x + (size_t)i*DD);
  float acc = 0.f;
#pragma unroll
  for (int c=0;c<16;c++){
    float4 v = xr[c];
    acc = fmaf(v.x,v.x,acc); acc = fmaf(v.y,v.y,acc);
    acc = fmaf(v.z,v.z,acc); acc = fmaf(v.w,v.w,acc);
  }
  sq[i] = acc;
}

// ---------------- K2a: sampled upper bound on the 50th-NN distance -------------
// Every 8th j (1024 samples/row); per-row ascending bitonic; Tub = 32nd sample
// +1ulp. P(bound < true 50th) ~ Hypergeom(8192,50,1024)>=32 tail ~ 1e-15.
// E[candidates under bound] = 256, P(>1024) ~ 1e-9 (CBUF=1024 in k_cand).
__global__ __launch_bounds__(256) void k_samp(const float* __restrict__ x, const float* __restrict__ sq,
                                              float* __restrict__ Tub){
  __shared__ float xi[ROWS*DD];
  __shared__ float sqi[ROWS];
  __shared__ unsigned samp[ROWS*SBUF]; // 32KB
  const int tid = threadIdx.x;
  const int i0 = blockIdx.x * ROWS;
  for (int t = tid; t < ROWS*DD; t += 256) xi[t] = x[(size_t)i0*DD + t];
  if (tid < ROWS) sqi[tid] = sq[i0+tid];
  __syncthreads();
  for (int ss = 0; ss < 4; ++ss){
    const int s = ss*256 + tid;
    const int j = s*8;
    const float4* xj = (const float4*)(x + (size_t)j*DD);
    float acc[ROWS];
#pragma unroll
    for (int r=0;r<ROWS;r++) acc[r]=0.f;
#pragma unroll
    for (int c=0;c<16;c++){
      const float4 a = xj[c];
#pragma unroll
      for (int r=0;r<ROWS;r++){
        const float4 wv = ((const float4*)(xi + r*DD))[c];
        acc[r] = fmaf(a.x,wv.x,acc[r]); acc[r] = fmaf(a.y,wv.y,acc[r]);
        acc[r] = fmaf(a.z,wv.z,acc[r]); acc[r] = fmaf(a.w,wv.w,acc[r]);
      }
    }
    const float sj = sq[j];
#pragma unroll
    for (int r=0;r<ROWS;r++){
      float d = (sqi[r] + sj) - 2.f*acc[r];
      if (d < 0.f) d = 0.f;
      samp[r*SBUF + s] = __float_as_uint(d); // positive floats: bits monotone
    }
  }
  __syncthreads();
  for (int k = 2; k <= SBUF; k <<= 1){
    for (int jj = k >> 1; jj > 0; jj >>= 1){
      for (int mm = tid; mm < SBUF/2; mm += 256){
        int i = ((mm & ~(jj-1)) << 1) | (mm & (jj-1));
        int p = i | jj;
        bool up = ((i & k) == 0);
#pragma unroll
        for (int r = 0; r < ROWS; ++r){
          unsigned a = samp[r*SBUF+i], b = samp[r*SBUF+p];
          if ((a > b) == up){ samp[r*SBUF+i] = b; samp[r*SBUF+p] = a; }
        }
      }
      __syncthreads();
    }
  }
  if (tid < ROWS) Tub[i0+tid] = __uint_as_float(samp[tid*SBUF + 31] + 1u);
}

// ---------------- K2b: collect candidates, exact top-50 via bitonic -------------
__global__ __launch_bounds__(256) void k_cand(const float* __restrict__ x, const float* __restrict__ sq,
                                              const float* __restrict__ Tub,
                                              float* __restrict__ res, unsigned short* __restrict__ nn16){
  __shared__ float xi[ROWS_C*DD];
  __shared__ float sqi[ROWS_C];
  __shared__ float tub[ROWS_C];
  __shared__ unsigned long long cand[ROWS_C*CBUF]; // 32KB
  __shared__ unsigned ccnt[ROWS_C];
  __shared__ int wid;
  const int tid = threadIdx.x;
  const int i0 = blockIdx.x * ROWS_C;
  for (int t = tid; t < ROWS_C*DD; t += 256) xi[t] = x[(size_t)i0*DD + t];
  for (int t = tid; t < ROWS_C*CBUF; t += 256) cand[t] = ~0ULL;
  if (tid < ROWS_C){ sqi[tid] = sq[i0+tid]; tub[tid] = Tub[i0+tid]; ccnt[tid] = 0u; }
  __syncthreads();
  for (int jo = 0; jo < NN; jo += 512){
    const int j = jo + tid*2;
    const float* xj = x + (size_t)j*DD;
    float acc0[ROWS_C], acc1[ROWS_C];
#pragma unroll
    for (int r=0;r<ROWS_C;r++){ acc0[r]=0.f; acc1[r]=0.f; }
#pragma unroll
    for (int c=0;c<16;c++){
      const float4 a = ((const float4*)xj)[c];
      const float4 b = ((const float4*)(xj+DD))[c];
#pragma unroll
      for (int r=0;r<ROWS_C;r++){
        const float4 wv = ((const float4*)(xi + r*DD))[c];
        acc0[r] = fmaf(a.x,wv.x,acc0[r]); acc0[r] = fmaf(a.y,wv.y,acc0[r]);
        acc0[r] = fmaf(a.z,wv.z,acc0[r]); acc0[r] = fmaf(a.w,wv.w,acc0[r]);
        acc1[r] = fmaf(b.x,wv.x,acc1[r]); acc1[r] = fmaf(b.y,wv.y,acc1[r]);
        acc1[r] = fmaf(b.z,wv.z,acc1[r]); acc1[r] = fmaf(b.w,wv.w,acc1[r]);
      }
    }
    const float sj0 = sq[j], sj1 = sq[j+1];
#pragma unroll
    for (int r=0;r<ROWS_C;r++){
      float d0 = (sqi[r] + sj0) - 2.f*acc0[r];
      float d1 = (sqi[r] + sj1) - 2.f*acc1[r];
      if (d0 < tub[r]){
        unsigned pos = atomicAdd(&ccnt[r], 1u);
        if (pos < CBUF){
          unsigned u = __float_as_uint(d0);
          u = ((int)u < 0) ? ~u : (u | 0x80000000u);
          cand[r*CBUF+pos] = (((unsigned long long)u) << 13) | (unsigned)j;
        }
      }
      if (d1 < tub[r]){
        unsigned pos = atomicAdd(&ccnt[r], 1u);
        if (pos < CBUF){
          unsigned u = __float_as_uint(d1);
          u = ((int)u < 0) ? ~u : (u | 0x80000000u);
          cand[r*CBUF+pos] = (((unsigned long long)u) << 13) | (unsigned)(j+1);
        }
      }
    }
  }
  __syncthreads();
  if (tid == 0){
    unsigned mx = 0;
    for (int r = 0; r < ROWS_C; ++r) mx = (ccnt[r] > mx) ? ccnt[r] : mx;
    wid = (mx > 512u) ? 1024 : 512;
  }
  __syncthreads();
  const int W = wid;
  for (int k = 2; k <= W; k <<= 1){
    for (int jj = k >> 1; jj > 0; jj >>= 1){
      for (int mm = tid; mm < W/2; mm += 256){
        int i = ((mm & ~(jj-1)) << 1) | (mm & (jj-1));
        int p = i | jj;
        bool up = ((i & k) == 0);
#pragma unroll
        for (int r = 0; r < ROWS_C; ++r){
          unsigned long long a = cand[r*CBUF+i], bb = cand[r*CBUF+p];
          if ((a > bb) == up){ cand[r*CBUF+i] = bb; cand[r*CBUF+p] = a; }
        }
      }
      __syncthreads();
    }
  }
  // outputs: 4 waves, 1 row each
  const int w = tid >> 6, lane = tid & 63;
  {
    const int r = w;
    unsigned long long kk = cand[r*CBUF + lane];
    float e = 0.f;
    if (lane < KKDE){
      unsigned u = (unsigned)(kk >> 13);
      u = (u & 0x80000000u) ? (u & 0x7FFFFFFFu) : ~u;
      float d = __uint_as_float(u);
      e = expf(-d / 30.f);
    }
#pragma unroll
    for (int off = 32; off; off >>= 1) e += __shfl_down(e, off);
    if (lane == 0) res[i0+r] = e / 1500.f;
    if (lane < KRIPS) nn16[(size_t)(i0+r)*16 + lane] = (unsigned short)(kk & 8191ULL);
  }
}

// ---------------- K3: max of res ------------------------------------------------
__global__ __launch_bounds__(1024) void k_max(const float* __restrict__ res, float* __restrict__ maxr){
  __shared__ float s[1024];
  float m = 0.f;
  for (int t = threadIdx.x; t < NN; t += 1024) m = fmaxf(m, res[t]);
  s[threadIdx.x] = m; __syncthreads();
  for (int o = 512; o; o >>= 1){ if (threadIdx.x < o) s[threadIdx.x] = fmaxf(s[threadIdx.x], s[threadIdx.x+o]); __syncthreads(); }
  if (threadIdx.x == 0) maxr[0] = s[0];
}

// ---------------- K4: stable argsort of density via 64KB LDS bitonic ------------
__global__ __launch_bounds__(1024) void k_sort(const float* __restrict__ res, const float* __restrict__ maxr,
                                               unsigned* __restrict__ sidx, float* __restrict__ dens_s,
                                               unsigned short* __restrict__ rankv){
  __shared__ unsigned long long keys[NN]; // 64KB
  const float mr = maxr[0];
  for (int t = threadIdx.x; t < NN; t += 1024){
    float dnv = res[t] / mr;
    keys[t] = (((unsigned long long)__float_as_uint(dnv)) << 13) | (unsigned)t;
  }
  __syncthreads();
  for (int k = 2; k <= NN; k <<= 1){
    for (int j = k >> 1; j > 0; j >>= 1){
      for (int m = threadIdx.x; m < NN/2; m += 1024){
        int i = ((m & ~(j-1)) << 1) | (m & (j-1));
        int p = i | j;
        bool up = ((i & k) == 0);
        unsigned long long a = keys[i], b = keys[p];
        if ((a > b) == up){ keys[i] = b; keys[p] = a; }
      }
      __syncthreads();
    }
  }
  for (int t = threadIdx.x; t < NN; t += 1024){
    unsigned long long kk = keys[t];
    unsigned idx = (unsigned)(kk & 8191ULL);
    sidx[t] = idx;
    dens_s[t] = __uint_as_float((unsigned)(kk >> 13));
    rankv[idx] = (unsigned short)t;
  }
}

// ---------------- K5: upward neighbor lists, sorted desc, grouped-transposed ----
// Layout for k_uf: group g covers iterations p = 4g+3-t (t=0..3, processed in t
// order). ups_t[g*64 + t*16 + k] = k-th largest upward rank of point (4g+3-t),
// 0-padded (rank 0 can never be an upward neighbour since u > p >= 0).
__global__ __launch_bounds__(256) void k_ups(const unsigned* __restrict__ sidx, const unsigned short* __restrict__ rankv,
                                             const unsigned short* __restrict__ nn16, unsigned short* __restrict__ ups_t){
  int p = blockIdx.x*256 + threadIdx.x;
  unsigned orig = sidx[p];
  unsigned short out[16];
  int cnt = 0;
  for (int k = 0; k < 16; ++k){
    unsigned r = rankv[nn16[(size_t)orig*16 + k]];
    if ((int)r > p){
      int q = cnt++;
      while (q > 0 && out[q-1] < (unsigned short)r){ out[q] = out[q-1]; --q; }
      out[q] = (unsigned short)r;
    }
  }
  for (int k = cnt; k < 16; ++k) out[k] = 0;
  const int g = p >> 2, t = 3 - (p & 3);
  unsigned short* dst = ups_t + (size_t)g*64 + t*16;
  for (int k = 0; k < 16; ++k) dst[k] = out[k];
}

// ---------------- K6: single-wave union-find sweep, eager-root invariant --------
// Invariant: par[x] == live root of x's component for every processed x (and
// par[x]==x for unprocessed/roots). find == 1 LDS read. Merges (one per peak)
// repair the invariant with a gated full pointer-halving sweep.
__global__ __launch_bounds__(64) void k_uf(const unsigned short* __restrict__ ups_t, int* __restrict__ death_out){
  __shared__ unsigned short par[NN];   // 16KB
  __shared__ unsigned short death[NN]; // 16KB
  __shared__ unsigned short hasm[NN];  // 16KB: 1 iff any par[x]==root was ever written
  unsigned* par32 = (unsigned*)par;
  const int lane = threadIdx.x;
  for (int t = lane; t < NN/2; t += 64){
    par32[t] = (unsigned)(((2*t+1) << 16) | (2*t));
    ((unsigned*)death)[t] = 0xFFFFFFFFu;
    ((unsigned*)hasm)[t] = 0u;
  }
  __syncthreads();
  // global prefetch pipeline (depth 3) for neighbor groups
  unsigned short nb0 = ups_t[(size_t)2047*64 + lane];
  unsigned short nb1 = ups_t[(size_t)2046*64 + lane];
  unsigned short nb2 = ups_t[(size_t)2045*64 + lane];
  for (int g = 2047; g >= 0; --g){
    const unsigned u = nb0;
    nb0 = nb1; nb1 = nb2;
    if (g >= 3) nb2 = ups_t[(size_t)(g-3)*64 + lane];
    const unsigned long long ball = __ballot(u != 0u);
    if (ball == 0ULL) continue;
    int root = par[u];               // 1-hop find for 4 iterations at once
    const int p3 = 4*g + 3;
#pragma unroll
    for (int t = 0; t < 4; ++t){
      if (((ball >> (16*t)) & 0xFFFFULL) == 0ULL) continue; // peak: par[p]=p stays
      const int p = p3 - t;
      const int r_up = __builtin_amdgcn_readlane(root, 16*t); // lane 16t holds u_max
      if (lane == 16*t){ par[p] = (unsigned short)r_up; hasm[r_up] = 1; }
      const bool mine = (u != 0u) && ((lane >> 4) == t);
      const bool cond = mine && (root != r_up);
      const unsigned long long dmask = __ballot(cond);
      if (dmask != 0ULL){
        int hm = 0;
        if (cond) hm = hasm[root];
        const bool sweep = (__ballot(cond && (hm != 0)) != 0ULL);
        if (cond){
          death[root] = (unsigned short)p;  // every entry dies exactly once
          par[root]   = (unsigned short)r_up;
          hasm[r_up]  = 1;
        }
        if (sweep){
          for (int x2 = lane; x2 < NN/2; x2 += 64){
            unsigned v = par32[x2];
            unsigned lo = v & 0xFFFFu, hi = v >> 16;
            unsigned lo2 = par[lo], hi2 = par[hi];
            unsigned nv = lo2 | (hi2 << 16);
            if (nv != v) par32[x2] = nv;
          }
        }
        root = par[root];              // refresh in-register roots (all live after)
      }
      root = (u == (unsigned)p) ? r_up : root; // in-group attach fixup
    }
  }
  __syncthreads();
  for (int t = lane; t < NN; t += 64){
    unsigned short d = death[t];
    death_out[t] = (d == 0xFFFFu) ? -1 : (int)d;
  }
}

// ---------------- K7: loss (sum + top-10 by (pers, entry) lexicographic) --------
__global__ __launch_bounds__(1024) void k_loss(const int* __restrict__ death, const float* __restrict__ dens_s,
                                               float* __restrict__ out){
  __shared__ float sred[1024];
  __shared__ unsigned long long kred[1024];
  __shared__ unsigned long long sel[10];
  const int tid = threadIdx.x;
  float s = 0.f;
  for (int e = tid; e < NN; e += 1024){
    int dr = death[e];
    if (dr >= 0) s += dens_s[e] - dens_s[dr];
  }
  sred[tid] = s; __syncthreads();
  for (int o = 512; o; o >>= 1){ if (tid < o) sred[tid] += sred[tid+o]; __syncthreads(); }
  const float S = sred[0];
  unsigned long long last = ~0ULL;
  for (int t = 0; t < 10; ++t){
    unsigned long long km = 0ULL;
    for (int e = tid; e < NN; e += 1024){
      int dr = death[e];
      if (dr >= 0){
        float pers = dens_s[e] - dens_s[dr];
        unsigned long long k = (((unsigned long long)__float_as_uint(pers)) << 13) | (unsigned)e;
        if (k < last && k > km) km = k;
      }
    }
    kred[tid] = km; __syncthreads();
    for (int o = 512; o; o >>= 1){ if (tid < o) kred[tid] = (kred[tid] > kred[tid+o]) ? kred[tid] : kred[tid+o]; __syncthreads(); }
    unsigned long long st = kred[0];
    if (tid == 0) sel[t] = st;
    last = st;
    __syncthreads();
  }
  if (tid == 0){
    float top = 0.f;
    for (int t = 0; t < 10; ++t){
      if (sel[t]) top += __uint_as_float((unsigned)(sel[t] >> 13));
    }
    float strong = 0.f, dest0 = 0.f, dest1 = 0.f;
    if (sel[0]){
      unsigned e0 = (unsigned)(sel[0] & 8191ULL);
      dest0 = dens_s[e0]; dest1 = dens_s[death[e0]];
    }
    for (int t = 1; t < 10; ++t){
      if (!sel[t]) continue;
      unsigned e = (unsigned)(sel[t] & 8191ULL);
      float a = dens_s[e] - dest0;
      float b = dens_s[death[e]] - dest1;
      strong += sqrtf(a*a + b*b);
    }
    float weak = (S - top) / 1.41421356237309515f;
    out[0] = weak + strong;
  }
}

// ---------------- launch --------------------------------------------------------
extern "C" void kernel_launch(void* const* d_in, const int* in_sizes, int n_in,
                              void* d_out, int out_size, void* d_ws, size_t ws_size,
                              hipStream_t stream){
  const float* x = (const float*)d_in[0];
  char* w = (char*)d_ws;
  float*          sq     = (float*)(w + 0);
  float*          res    = (float*)(w + 32768);
  float*          maxr   = (float*)(w + 65536);
  float*          Tub    = (float*)(w + 65792);
  unsigned*       sidx   = (unsigned*)(w + 98560);
  float*          dens_s = (float*)(w + 131328);
  unsigned short* rankv  = (unsigned short*)(w + 164096);
  unsigned short* nn16   = (unsigned short*)(w + 180480);
  unsigned short* ups_t  = (unsigned short*)(w + 442624);
  int*            death  = (int*)(w + 704768);

  k_sq  <<<NN/256, 256, 0, stream>>>(x, sq);
  k_samp<<<NN/ROWS, 256, 0, stream>>>(x, sq, Tub);
  k_cand<<<NN/ROWS_C, 256, 0, stream>>>(x, sq, Tub, res, nn16);
  k_max <<<1, 1024, 0, stream>>>(res, maxr);
  k_sort<<<1, 1024, 0, stream>>>(res, maxr, sidx, dens_s, rankv);
  k_ups <<<NN/256, 256, 0, stream>>>(sidx, rankv, nn16, ups_t);
  k_uf  <<<1, 64, 0, stream>>>(ups_t, death);
  k_loss<<<1, 1024, 0, stream>>>(death, dens_s, (float*)d_out);
}